// Round 1
// baseline (843.143 us; speedup 1.0000x reference)
//
#include <hip/hip_runtime.h>
#include <hip/hip_bf16.h>
#include <math.h>

#define B_ 512
#define D_ 256
#define NH_ 4
#define NN_ 512
#define NTOT_ 2048
#define DH_ 64
#define KSTEPS 8

__device__ __forceinline__ float gelu_exact(float x) {
  return 0.5f * x * (1.0f + erff(x * 0.70710678118654752f));
}

__device__ __forceinline__ float blockReduceSum256(float v, float* red) {
  int t = threadIdx.x;
  red[t] = v; __syncthreads();
  #pragma unroll
  for (int st = 128; st > 0; st >>= 1) {
    if (t < st) red[t] += red[t + st];
    __syncthreads();
  }
  float r = red[0];
  __syncthreads();
  return r;
}

// Generic tiled f32 GEMM: out = epilogue(A[M,K] @ W[K,N] (+bias))
// ACT: 0 none, 1 relu, 2 gelu
// HEADW: W is (NH, 256, 512) per-head (D_y / D_x layout), N must be 2048
// MUL:   out *= mul   (for y = g * x_h)
// ADDTO: out = addto + out  (residual x update; addto may alias out)
// If gridDim.z > 1: split-K, writes raw partial sums to out + z*M*N (no epilogue)
template<int ACT, bool HEADW, bool MUL, bool ADDTO>
__global__ __launch_bounds__(256) void gemm_tile(
    const float* __restrict__ A, const float* __restrict__ W,
    const float* __restrict__ bias, const float* __restrict__ mul,
    const float* __restrict__ addto, float* __restrict__ out,
    int M, int N, int K, int kchunk)
{
  __shared__ float As[16][68];
  __shared__ float Bs[16][68];
  const int tid = threadIdx.x;
  const int row0 = blockIdx.y * 64;
  const int col0 = blockIdx.x * 64;
  const int k0 = blockIdx.z * kchunk;
  const int ty = tid >> 4, tx = tid & 15;
  const int ar = tid >> 4, ak = tid & 15;
  const int br = tid >> 6, bc = tid & 63;
  float acc[4][4] = {};
  for (int kk = k0; kk < k0 + kchunk; kk += 16) {
    #pragma unroll
    for (int i = 0; i < 4; i++) {
      int r = ar + i * 16;
      As[ak][r] = A[(size_t)(row0 + r) * K + kk + ak];
    }
    #pragma unroll
    for (int i = 0; i < 4; i++) {
      int kr = br + i * 4;
      int colg = col0 + bc;
      size_t widx;
      if (HEADW) {
        int h = colg >> 9;
        widx = ((size_t)(h * 256 + kk + kr)) * 512 + (colg & 511);
      } else {
        widx = (size_t)(kk + kr) * N + colg;
      }
      Bs[kr][bc] = W[widx];
    }
    __syncthreads();
    #pragma unroll
    for (int q = 0; q < 16; q++) {
      float4 av = *(const float4*)&As[q][ty * 4];
      float4 bv = *(const float4*)&Bs[q][tx * 4];
      float aa[4] = {av.x, av.y, av.z, av.w};
      float bb[4] = {bv.x, bv.y, bv.z, bv.w};
      #pragma unroll
      for (int i = 0; i < 4; i++)
        #pragma unroll
        for (int j = 0; j < 4; j++)
          acc[i][j] = fmaf(aa[i], bb[j], acc[i][j]);
    }
    __syncthreads();
  }
  const bool parts = (gridDim.z > 1);
  float* o = out + (parts ? (size_t)blockIdx.z * (size_t)M * N : (size_t)0);
  #pragma unroll
  for (int i = 0; i < 4; i++) {
    int r = row0 + ty * 4 + i;
    #pragma unroll
    for (int j = 0; j < 4; j++) {
      int c = col0 + tx * 4 + j;
      float v = acc[i][j];
      if (!parts) {
        if (bias) v += bias[c];
        if (ACT == 1) v = v > 0.f ? v : 0.f;
        else if (ACT == 2) v = gelu_exact(v);
        if (MUL) v *= mul[(size_t)r * N + c];
        if (ADDTO) v += addto[(size_t)r * N + c];
      }
      o[(size_t)r * N + c] = v;
    }
  }
}

// Sum nparts partial GEMM outputs, LayerNorm over 256 cols, optional out2 = out + addvec
__global__ __launch_bounds__(256) void k_ln_reduce(
    const float* __restrict__ in, int nparts, int stride,
    const float* __restrict__ g, const float* __restrict__ bta,
    const float* __restrict__ addvec, float* __restrict__ out,
    float* __restrict__ out2)
{
  __shared__ float red[256];
  int b = blockIdx.x, d = threadIdx.x;
  float v = 0.f;
  for (int p = 0; p < nparts; p++) v += in[(size_t)p * stride + (size_t)b * 256 + d];
  float mu = blockReduceSum256(v, red) * (1.f / 256.f);
  float c = v - mu;
  float var = blockReduceSum256(c * c, red) * (1.f / 256.f);
  float vn = c * rsqrtf(var + 1e-5f) * g[d] + bta[d];
  out[(size_t)b * 256 + d] = vn;
  if (out2) out2[(size_t)b * 256 + d] = vn + addvec[(size_t)b * 256 + d];
}

// a_k = sum_{j<k} (1-lam) lam^{k-1-j} (xw_j . x_k)_{b,h} * z_j ; a_cond = LN(a + b_y)
__global__ __launch_bounds__(256) void step_a(
    const float* __restrict__ x, const float* __restrict__ xw_hist,
    const float* __restrict__ z_hist, const float* __restrict__ b_y,
    const float* __restrict__ lna_g, const float* __restrict__ lna_b,
    const float* __restrict__ log_damp, int k, float* __restrict__ out)
{
  __shared__ float dots[KSTEPS][NH_];
  __shared__ float red[256];
  int b = blockIdx.x, t = threadIdx.x;
  int lane = t & 63, wv = t >> 6;  // wv == head for the dot phase
  float lam = 1.f / (1.f + expf(-log_damp[0]));
  const float* xb = x + (size_t)b * NTOT_;
  float xv[8];
  #pragma unroll
  for (int i = 0; i < 8; i++) xv[i] = xb[t * 8 + i];
  for (int j = 0; j < k; j++) {
    const float* xwb = xw_hist + ((size_t)j * B_ + b) * NTOT_;
    float s = 0.f;
    #pragma unroll
    for (int i = 0; i < 8; i++) s += xv[i] * xwb[t * 8 + i];
    #pragma unroll
    for (int off = 32; off > 0; off >>= 1) s += __shfl_down(s, off, 64);
    if (lane == 0) dots[j][wv] = s;
  }
  __syncthreads();
  int d = t;
  float av = 0.f, lp = 1.f;
  for (int j = k - 1; j >= 0; j--) {
    av += (1.f - lam) * lp * dots[j][d >> 6] *
          z_hist[((size_t)j * B_ + b) * D_ + d];
    lp *= lam;
  }
  av += b_y[(size_t)b * D_ + d];
  float mu = blockReduceSum256(av, red) * (1.f / 256.f);
  float c = av - mu;
  float var = blockReduceSum256(c * c, red) * (1.f / 256.f);
  out[(size_t)b * D_ + d] = c * rsqrtf(var + 1e-5f) * lna_g[d] + lna_b[d];
}

// xw = x / (||x||_head + 1e-8), per (b, head) over 512 neurons
__global__ __launch_bounds__(256) void k_xwrite(
    const float* __restrict__ x, float* __restrict__ xw)
{
  int b = blockIdx.x, t = threadIdx.x;
  const float* xb = x + (size_t)b * NTOT_;
  float v[8]; float s = 0.f;
  #pragma unroll
  for (int i = 0; i < 8; i++) { v[i] = xb[t * 8 + i]; s += v[i] * v[i]; }
  #pragma unroll
  for (int m = 1; m < 64; m <<= 1) s += __shfl_xor(s, m, 64);
  float inv = 1.f / (sqrtf(s) + 1e-8f);
  #pragma unroll
  for (int i = 0; i < 8; i++) xw[(size_t)b * NTOT_ + t * 8 + i] = v[i] * inv;
}

// v = tanh(gbuf[b,:] @ vh_w2 + vh_b2)
__global__ __launch_bounds__(128) void k_value2(
    const float* __restrict__ gbuf, const float* __restrict__ w2,
    const float* __restrict__ b2, float* __restrict__ out)
{
  int b = blockIdx.x * blockDim.x + threadIdx.x;
  float s = 0.f;
  #pragma unroll 8
  for (int i = 0; i < 128; i++) s += gbuf[(size_t)b * 128 + i] * w2[i];
  out[b] = tanhf(s + b2[0]);
}

extern "C" void kernel_launch(void* const* d_in, const int* in_sizes, int n_in,
                              void* d_out, int out_size, void* d_ws, size_t ws_size,
                              hipStream_t stream) {
  const float* boards   = (const float*)d_in[0];
  const float* enc_w1   = (const float*)d_in[1];
  const float* enc_b1   = (const float*)d_in[2];
  const float* enc_ln_g = (const float*)d_in[3];
  const float* enc_ln_b = (const float*)d_in[4];
  const float* enc_w2   = (const float*)d_in[5];
  const float* enc_b2   = (const float*)d_in[6];
  const float* xinit_w  = (const float*)d_in[7];
  const float* xinit_b  = (const float*)d_in[8];
  const float* D_y      = (const float*)d_in[9];
  const float* E        = (const float*)d_in[10];
  const float* D_x      = (const float*)d_in[11];
  const float* By_w     = (const float*)d_in[12];
  const float* Bx_w     = (const float*)d_in[13];
  const float* lna_g    = (const float*)d_in[14];
  const float* lna_b    = (const float*)d_in[15];
  const float* lnz_g    = (const float*)d_in[16];
  const float* lnz_b    = (const float*)d_in[17];
  const float* log_damp = (const float*)d_in[18];
  const float* vh_w1    = (const float*)d_in[19];
  const float* vh_b1    = (const float*)d_in[20];
  const float* vh_w2    = (const float*)d_in[21];
  const float* vh_b2    = (const float*)d_in[22];
  float* outp = (float*)d_out;

  float* ws = (float*)d_ws;
  size_t o = 0;
  float* x      = ws + o; o += (size_t)B_ * NTOT_;            // 512x2048
  float* xw     = ws + o; o += (size_t)KSTEPS * B_ * NTOT_;   // 8x512x2048
  float* zh     = ws + o; o += (size_t)KSTEPS * B_ * D_;      // 8x512x256
  float* hpre   = ws + o; o += (size_t)B_ * D_;
  float* h      = ws + o; o += (size_t)B_ * D_;
  float* bvec   = ws + o; o += (size_t)B_ * D_;
  float* b_y    = ws + o; o += (size_t)B_ * D_;
  float* b_x    = ws + o; o += (size_t)B_ * D_;
  float* acond  = ws + o; o += (size_t)B_ * D_;
  float* y      = ws + o; o += (size_t)B_ * NTOT_;
  float* zparts = ws + o; o += (size_t)8 * B_ * D_;
  float* zbx    = ws + o; o += (size_t)B_ * D_;
  float* gbuf   = ws + o; o += (size_t)B_ * 128;

  // ---- encoder ----
  gemm_tile<2,false,false,false><<<dim3(4,8,1),256,0,stream>>>(
      boards, enc_w1, enc_b1, nullptr, nullptr, hpre, B_, D_, 768, 768);
  k_ln_reduce<<<B_,256,0,stream>>>(hpre, 1, 0, enc_ln_g, enc_ln_b, nullptr, h, nullptr);
  gemm_tile<0,false,false,false><<<dim3(4,8,1),256,0,stream>>>(
      h, enc_w2, enc_b2, nullptr, nullptr, bvec, B_, D_, D_, D_);
  gemm_tile<1,false,false,false><<<dim3(32,8,1),256,0,stream>>>(
      bvec, xinit_w, xinit_b, nullptr, nullptr, x, B_, NTOT_, D_, D_);
  gemm_tile<0,false,false,false><<<dim3(4,8,1),256,0,stream>>>(
      bvec, By_w, nullptr, nullptr, nullptr, b_y, B_, D_, D_, D_);
  gemm_tile<0,false,false,false><<<dim3(4,8,1),256,0,stream>>>(
      bvec, Bx_w, nullptr, nullptr, nullptr, b_x, B_, D_, D_, D_);

  // ---- K thinking steps ----
  for (int k = 0; k < KSTEPS; k++) {
    step_a<<<B_,256,0,stream>>>(x, xw, zh, b_y, lna_g, lna_b, log_damp, k, acond);
    // y = relu(a_cond @ D_y) * x
    gemm_tile<1,true,true,false><<<dim3(32,8,1),256,0,stream>>>(
        acond, D_y, nullptr, x, nullptr, y, B_, NTOT_, D_, D_);
    // z_pre (split-K over 2048)
    gemm_tile<0,false,false,false><<<dim3(4,8,8),256,0,stream>>>(
        y, E, nullptr, nullptr, nullptr, zparts, B_, D_, NTOT_, 256);
    // z = LN(sum parts); zbx = z + b_x
    k_ln_reduce<<<B_,256,0,stream>>>(zparts, 8, B_*D_, lnz_g, lnz_b, b_x,
                                     zh + (size_t)k * B_ * D_, zbx);
    // x += relu(zbx @ D_x)   (in-place)
    gemm_tile<1,true,false,true><<<dim3(32,8,1),256,0,stream>>>(
        zbx, D_x, nullptr, nullptr, x, x, B_, NTOT_, D_, D_);
    if (k < KSTEPS - 1)
      k_xwrite<<<B_,256,0,stream>>>(x, xw + (size_t)k * B_ * NTOT_);
  }

  // ---- value head ----
  gemm_tile<2,false,false,false><<<dim3(2,8,1),256,0,stream>>>(
      zh + (size_t)(KSTEPS-1) * B_ * D_, vh_w1, vh_b1, nullptr, nullptr, gbuf,
      B_, 128, D_, D_);
  k_value2<<<4,128,0,stream>>>(gbuf, vh_w2, vh_b2, outp);
}

// Round 2
// 450.045 us; speedup vs baseline: 1.8735x; 1.8735x over previous
//
#include <hip/hip_runtime.h>
#include <hip/hip_bf16.h>
#include <math.h>

#define B_ 512
#define D_ 256
#define NH_ 4
#define NN_ 512
#define NTOT_ 2048
#define DH_ 64
#define KSTEPS 8

typedef __attribute__((ext_vector_type(8))) short bf16x8;
typedef __attribute__((ext_vector_type(4))) float f32x4;

__device__ __forceinline__ float gelu_exact(float x) {
  return 0.5f * x * (1.0f + erff(x * 0.70710678118654752f));
}

__device__ __forceinline__ unsigned short f2b(float f) {
  union { float f; unsigned int u; } x; x.f = f;
  unsigned int u = x.u;
  unsigned int r = (u + 0x7FFFu + ((u >> 16) & 1u)) >> 16;
  return (unsigned short)r;
}

__device__ __forceinline__ float blockReduceSum256(float v, float* red) {
  int t = threadIdx.x;
  red[t] = v; __syncthreads();
  #pragma unroll
  for (int st = 128; st > 0; st >>= 1) {
    if (t < st) red[t] += red[t + st];
    __syncthreads();
  }
  float r = red[0];
  __syncthreads();
  return r;
}

// ---------------- bf16 MFMA GEMM ----------------
// A [M][K] bf16 row-major, W [N][K] bf16 row-major (i.e. W^T of the K x N weight).
// out = epilogue(A @ W^T_kn)
// EPI: 0 = bias + relu -> f32
//      1 = relu * mul  -> bf16
//      2 = raw partial (split-K part blockIdx.z) -> f32
//      3 = relu + addto -> f32
// Tile 64x64, BK=64, 256 threads (4 waves, 2x2 of 32x32 wave tiles).
template<int EPI>
__global__ __launch_bounds__(256) void gemm_mfma(
    const unsigned short* __restrict__ A, const unsigned short* __restrict__ W,
    const float* __restrict__ bias, const float* __restrict__ mul,
    const float* __restrict__ addto, float* __restrict__ outf,
    unsigned short* __restrict__ outb, int K, int N, int kchunk)
{
  __shared__ __align__(16) unsigned short As[64 * 64];
  __shared__ __align__(16) unsigned short Ws[64 * 64];
  const int t = threadIdx.x;
  const int lane = t & 63;
  const int w = t >> 6;
  const int wr = (w >> 1) * 32, wc = (w & 1) * 32;
  const int row0 = blockIdx.y * 64, col0 = blockIdx.x * 64;
  const int k0 = blockIdx.z * kchunk;

  f32x4 acc[2][2];
  #pragma unroll
  for (int i = 0; i < 2; i++)
    #pragma unroll
    for (int j = 0; j < 2; j++)
      acc[i][j] = (f32x4){0.f, 0.f, 0.f, 0.f};

  const int ar = t >> 3;   // 0..31 (row within half-tile)
  const int ac = t & 7;    // 16B chunk within 128B row

  for (int kt = 0; kt < kchunk; kt += 64) {
    const int kk = k0 + kt;
    // stage A and W tiles, swizzled content: LDS slot (row, c) holds global chunk c ^ (row&7)
    #pragma unroll
    for (int p = 0; p < 2; p++) {
      int row = p * 32 + ar;
      int cs = ac ^ (row & 7);
      bf16x8 va = *(const bf16x8*)&A[(size_t)(row0 + row) * K + kk + cs * 8];
      *(bf16x8*)&As[row * 64 + ac * 8] = va;
      bf16x8 vb = *(const bf16x8*)&W[(size_t)(col0 + row) * K + kk + cs * 8];
      *(bf16x8*)&Ws[row * 64 + ac * 8] = vb;
    }
    __syncthreads();
    #pragma unroll
    for (int ks = 0; ks < 64; ks += 32) {
      bf16x8 af[2], bfr[2];
      #pragma unroll
      for (int i = 0; i < 2; i++) {
        int r = wr + i * 16 + (lane & 15);
        int cb = (ks + (lane >> 4) * 8) * 2;
        cb ^= (r & 7) << 4;
        af[i] = *(const bf16x8*)((const char*)As + r * 128 + cb);
      }
      #pragma unroll
      for (int j = 0; j < 2; j++) {
        int c = wc + j * 16 + (lane & 15);
        int cb = (ks + (lane >> 4) * 8) * 2;
        cb ^= (c & 7) << 4;
        bfr[j] = *(const bf16x8*)((const char*)Ws + c * 128 + cb);
      }
      #pragma unroll
      for (int i = 0; i < 2; i++)
        #pragma unroll
        for (int j = 0; j < 2; j++)
          acc[i][j] = __builtin_amdgcn_mfma_f32_16x16x32_bf16(af[i], bfr[j], acc[i][j], 0, 0, 0);
    }
    __syncthreads();
  }

  const int cr = (lane >> 4) * 4;
  const int cc = lane & 15;
  #pragma unroll
  for (int i = 0; i < 2; i++) {
    #pragma unroll
    for (int j = 0; j < 2; j++) {
      #pragma unroll
      for (int q = 0; q < 4; q++) {
        int r = row0 + wr + i * 16 + cr + q;
        int c = col0 + wc + j * 16 + cc;
        float v = acc[i][j][q];
        if (EPI == 0) {
          v += bias[c]; v = fmaxf(v, 0.f);
          outf[(size_t)r * N + c] = v;
        } else if (EPI == 1) {
          v = fmaxf(v, 0.f) * mul[(size_t)r * N + c];
          outb[(size_t)r * N + c] = f2b(v);
        } else if (EPI == 2) {
          outf[(size_t)blockIdx.z * (512 * (size_t)N) + (size_t)r * N + c] = v;
        } else {
          v = fmaxf(v, 0.f) + addto[(size_t)r * N + c];
          outf[(size_t)r * N + c] = v;
        }
      }
    }
  }
}

// ---------------- f32 tiled GEMM (encoder / value head only) ----------------
// ACT: 0 none, 1 relu, 2 gelu. Split-K when gridDim.z > 1 (raw partials).
template<int ACT>
__global__ __launch_bounds__(256) void gemm_tile(
    const float* __restrict__ A, const float* __restrict__ W,
    const float* __restrict__ bias, float* __restrict__ out,
    int M, int N, int K, int kchunk)
{
  __shared__ float As[16][68];
  __shared__ float Bs[16][68];
  const int tid = threadIdx.x;
  const int row0 = blockIdx.y * 64;
  const int col0 = blockIdx.x * 64;
  const int k0 = blockIdx.z * kchunk;
  const int ty = tid >> 4, tx = tid & 15;
  const int ar = tid >> 4, ak = tid & 15;
  const int br = tid >> 6, bc = tid & 63;
  float acc[4][4] = {};
  for (int kk = k0; kk < k0 + kchunk; kk += 16) {
    #pragma unroll
    for (int i = 0; i < 4; i++) {
      int r = ar + i * 16;
      As[ak][r] = A[(size_t)(row0 + r) * K + kk + ak];
    }
    #pragma unroll
    for (int i = 0; i < 4; i++) {
      int kr = br + i * 4;
      Bs[kr][bc] = W[(size_t)(kk + kr) * N + col0 + bc];
    }
    __syncthreads();
    #pragma unroll
    for (int q = 0; q < 16; q++) {
      float4 av = *(const float4*)&As[q][ty * 4];
      float4 bv = *(const float4*)&Bs[q][tx * 4];
      float aa[4] = {av.x, av.y, av.z, av.w};
      float bb[4] = {bv.x, bv.y, bv.z, bv.w};
      #pragma unroll
      for (int i = 0; i < 4; i++)
        #pragma unroll
        for (int j = 0; j < 4; j++)
          acc[i][j] = fmaf(aa[i], bb[j], acc[i][j]);
    }
    __syncthreads();
  }
  const bool parts = (gridDim.z > 1);
  float* o = out + (parts ? (size_t)blockIdx.z * (size_t)M * N : (size_t)0);
  #pragma unroll
  for (int i = 0; i < 4; i++) {
    int r = row0 + ty * 4 + i;
    #pragma unroll
    for (int j = 0; j < 4; j++) {
      int c = col0 + tx * 4 + j;
      float v = acc[i][j];
      if (!parts) {
        if (bias) v += bias[c];
        if (ACT == 1) v = v > 0.f ? v : 0.f;
        else if (ACT == 2) v = gelu_exact(v);
      }
      o[(size_t)r * N + c] = v;
    }
  }
}

// ---------------- transpose + f32->bf16 weight prep ----------------
// out[n][k] (bf16, row stride Kdim) from f32 input.
// HEAD: in is (NH,256,512): in[((n>>9)*256+k)*512 + (n&511)]; else in[k*Ndim + n].
template<bool HEAD>
__global__ __launch_bounds__(256) void k_transpose_cvt(
    const float* __restrict__ in, unsigned short* __restrict__ out,
    int Kdim, int Ndim)
{
  __shared__ float T[64][65];
  const int n0 = blockIdx.x * 64, k0 = blockIdx.y * 64;
  const int tx = threadIdx.x & 63, ty = threadIdx.x >> 6;
  #pragma unroll
  for (int i = 0; i < 16; i++) {
    int k = k0 + ty + i * 4;
    int n = n0 + tx;
    float v;
    if (HEAD) v = in[((size_t)(n >> 9) * 256 + k) * 512 + (n & 511)];
    else      v = in[(size_t)k * Ndim + n];
    T[ty + i * 4][tx] = v;
  }
  __syncthreads();
  #pragma unroll
  for (int i = 0; i < 16; i++) {
    int n = n0 + ty + i * 4;
    out[(size_t)n * Kdim + k0 + tx] = f2b(T[tx][ty + i * 4]);
  }
}

__global__ __launch_bounds__(256) void k_cvt(
    const float* __restrict__ in, unsigned short* __restrict__ out, int n4)
{
  int i = blockIdx.x * 256 + threadIdx.x;
  if (i < n4) {
    float4 v = ((const float4*)in)[i];
    unsigned int u0 = (unsigned int)f2b(v.x) | ((unsigned int)f2b(v.y) << 16);
    unsigned int u1 = (unsigned int)f2b(v.z) | ((unsigned int)f2b(v.w) << 16);
    ((uint2*)out)[i] = make_uint2(u0, u1);
  }
}

// ---------------- LN with partial-sum reduce ----------------
// v = sum_p in[p]; optional (+pre_bias, gelu); LN(g,bta) -> out (f32)
// optional out2_bf = bf16(LN + addvec)
__global__ __launch_bounds__(256) void k_ln_reduce(
    const float* __restrict__ in, int nparts, int stride,
    const float* __restrict__ pre_bias, int do_gelu,
    const float* __restrict__ g, const float* __restrict__ bta,
    const float* __restrict__ addvec, float* __restrict__ out,
    unsigned short* __restrict__ out2_bf)
{
  __shared__ float red[256];
  int b = blockIdx.x, d = threadIdx.x;
  float v = 0.f;
  for (int p = 0; p < nparts; p++) v += in[(size_t)p * stride + (size_t)b * 256 + d];
  if (pre_bias) v += pre_bias[d];
  if (do_gelu) v = gelu_exact(v);
  float mu = blockReduceSum256(v, red) * (1.f / 256.f);
  float c = v - mu;
  float var = blockReduceSum256(c * c, red) * (1.f / 256.f);
  float vn = c * rsqrtf(var + 1e-5f) * g[d] + bta[d];
  out[(size_t)b * 256 + d] = vn;
  if (out2_bf) out2_bf[(size_t)b * 256 + d] = f2b(vn + addvec[(size_t)b * 256 + d]);
}

// ---------------- step_a: xw(k-1) + low-rank rho dots + LN -> acond (bf16) ----------------
__global__ __launch_bounds__(256) void step_a(
    const float* __restrict__ x, float* __restrict__ xw_hist,
    const float* __restrict__ z_hist, const float* __restrict__ b_y,
    const float* __restrict__ lna_g, const float* __restrict__ lna_b,
    const float* __restrict__ log_damp, int k, unsigned short* __restrict__ out)
{
  __shared__ float dots[KSTEPS][NH_];
  __shared__ float red[256];
  int b = blockIdx.x, t = threadIdx.x;
  int lane = t & 63, wv = t >> 6;  // wv == head
  float lam = 1.f / (1.f + expf(-log_damp[0]));
  const float* xb = x + (size_t)b * NTOT_;
  float xv[8];
  #pragma unroll
  for (int i = 0; i < 8; i++) xv[i] = xb[t * 8 + i];

  if (k >= 1) {
    // xw_{k-1} = normalize_head(x); also dot_{k-1} = ||x||_head
    float s = 0.f;
    #pragma unroll
    for (int i = 0; i < 8; i++) s += xv[i] * xv[i];
    #pragma unroll
    for (int m = 1; m < 64; m <<= 1) s += __shfl_xor(s, m, 64);
    float inv = 1.f / (sqrtf(s) + 1e-8f);
    float* xwout = xw_hist + ((size_t)(k - 1) * B_ + b) * NTOT_;
    #pragma unroll
    for (int i = 0; i < 8; i++) xwout[t * 8 + i] = xv[i] * inv;
    if (lane == 0) dots[k - 1][wv] = s * inv;
  }
  for (int j = 0; j < k - 1; j++) {
    const float* xwb = xw_hist + ((size_t)j * B_ + b) * NTOT_;
    float s = 0.f;
    #pragma unroll
    for (int i = 0; i < 8; i++) s += xv[i] * xwb[t * 8 + i];
    #pragma unroll
    for (int off = 32; off > 0; off >>= 1) s += __shfl_down(s, off, 64);
    if (lane == 0) dots[j][wv] = s;
  }
  __syncthreads();

  int d = t;
  float av = 0.f, lp = 1.f;
  for (int j = k - 1; j >= 0; j--) {
    av += (1.f - lam) * lp * dots[j][d >> 6] * z_hist[((size_t)j * B_ + b) * D_ + d];
    lp *= lam;
  }
  av += b_y[(size_t)b * D_ + d];
  float mu = blockReduceSum256(av, red) * (1.f / 256.f);
  float c = av - mu;
  float var = blockReduceSum256(c * c, red) * (1.f / 256.f);
  out[(size_t)b * D_ + d] = f2b(c * rsqrtf(var + 1e-5f) * lna_g[d] + lna_b[d]);
}

// ---------------- value head tail ----------------
__global__ __launch_bounds__(128) void k_value2(
    const float* __restrict__ gbuf, const float* __restrict__ w2,
    const float* __restrict__ b2, float* __restrict__ out)
{
  int b = blockIdx.x * blockDim.x + threadIdx.x;
  float s = 0.f;
  #pragma unroll 8
  for (int i = 0; i < 128; i++) s += gbuf[(size_t)b * 128 + i] * w2[i];
  out[b] = tanhf(s + b2[0]);
}

extern "C" void kernel_launch(void* const* d_in, const int* in_sizes, int n_in,
                              void* d_out, int out_size, void* d_ws, size_t ws_size,
                              hipStream_t stream) {
  const float* boards   = (const float*)d_in[0];
  const float* enc_w1   = (const float*)d_in[1];
  const float* enc_b1   = (const float*)d_in[2];
  const float* enc_ln_g = (const float*)d_in[3];
  const float* enc_ln_b = (const float*)d_in[4];
  const float* enc_w2   = (const float*)d_in[5];
  const float* enc_b2   = (const float*)d_in[6];
  const float* xinit_w  = (const float*)d_in[7];
  const float* xinit_b  = (const float*)d_in[8];
  const float* D_y      = (const float*)d_in[9];
  const float* E        = (const float*)d_in[10];
  const float* D_x      = (const float*)d_in[11];
  const float* By_w     = (const float*)d_in[12];
  const float* Bx_w     = (const float*)d_in[13];
  const float* lna_g    = (const float*)d_in[14];
  const float* lna_b    = (const float*)d_in[15];
  const float* lnz_g    = (const float*)d_in[16];
  const float* lnz_b    = (const float*)d_in[17];
  const float* log_damp = (const float*)d_in[18];
  const float* vh_w1    = (const float*)d_in[19];
  const float* vh_b1    = (const float*)d_in[20];
  const float* vh_w2    = (const float*)d_in[21];
  const float* vh_b2    = (const float*)d_in[22];
  float* outp = (float*)d_out;

  float* ws = (float*)d_ws;
  size_t o = 0;
  float* x      = ws + o; o += (size_t)B_ * NTOT_;            // f32 state
  float* xw     = ws + o; o += (size_t)KSTEPS * B_ * NTOT_;   // f32 history
  float* zh     = ws + o; o += (size_t)KSTEPS * B_ * D_;      // f32 z history
  float* hparts = ws + o; o += (size_t)3 * B_ * D_;
  float* h      = ws + o; o += (size_t)B_ * D_;
  float* bvec   = ws + o; o += (size_t)B_ * D_;
  float* b_y    = ws + o; o += (size_t)B_ * D_;
  float* b_x    = ws + o; o += (size_t)B_ * D_;
  float* zparts = ws + o; o += (size_t)8 * B_ * D_;
  float* gbuf   = ws + o; o += (size_t)B_ * 128;
  unsigned short* DyT     = (unsigned short*)(ws + o); o += (size_t)NTOT_ * D_ / 2;
  unsigned short* DxT     = (unsigned short*)(ws + o); o += (size_t)NTOT_ * D_ / 2;
  unsigned short* ET      = (unsigned short*)(ws + o); o += (size_t)D_ * NTOT_ / 2;
  unsigned short* xinitT  = (unsigned short*)(ws + o); o += (size_t)NTOT_ * D_ / 2;
  unsigned short* bvec_bf = (unsigned short*)(ws + o); o += (size_t)B_ * D_ / 2;
  unsigned short* acond_bf= (unsigned short*)(ws + o); o += (size_t)B_ * D_ / 2;
  unsigned short* zbx_bf  = (unsigned short*)(ws + o); o += (size_t)B_ * D_ / 2;
  unsigned short* y_bf    = (unsigned short*)(ws + o); o += (size_t)B_ * NTOT_ / 2;

  // ---- one-time weight prep (bf16, transposed to [N][K]) ----
  k_transpose_cvt<true ><<<dim3(32, 4), 256, 0, stream>>>(D_y,     DyT,    256, 2048);
  k_transpose_cvt<true ><<<dim3(32, 4), 256, 0, stream>>>(D_x,     DxT,    256, 2048);
  k_transpose_cvt<false><<<dim3(4, 32), 256, 0, stream>>>(E,       ET,     2048, 256);
  k_transpose_cvt<false><<<dim3(32, 4), 256, 0, stream>>>(xinit_w, xinitT, 256, 2048);

  // ---- encoder (f32) ----
  gemm_tile<0><<<dim3(4, 8, 3), 256, 0, stream>>>(boards, enc_w1, nullptr, hparts,
                                                  B_, D_, 768, 256);
  k_ln_reduce<<<B_, 256, 0, stream>>>(hparts, 3, B_ * D_, enc_b1, 1,
                                      enc_ln_g, enc_ln_b, nullptr, h, nullptr);
  gemm_tile<0><<<dim3(4, 8, 1), 256, 0, stream>>>(h, enc_w2, enc_b2, bvec, B_, D_, D_, D_);
  k_cvt<<<dim3(B_ * D_ / 1024), 256, 0, stream>>>(bvec, bvec_bf, B_ * D_ / 4);
  gemm_tile<0><<<dim3(4, 8, 1), 256, 0, stream>>>(bvec, By_w, nullptr, b_y, B_, D_, D_, D_);
  gemm_tile<0><<<dim3(4, 8, 1), 256, 0, stream>>>(bvec, Bx_w, nullptr, b_x, B_, D_, D_, D_);
  // x0 = relu(b @ xinit_w + bias)  [bf16 MFMA]
  gemm_mfma<0><<<dim3(32, 8, 1), 256, 0, stream>>>(bvec_bf, xinitT, xinit_b, nullptr,
                                                   nullptr, x, nullptr, 256, 2048, 256);

  // ---- K thinking steps ----
  for (int k = 0; k < KSTEPS; k++) {
    step_a<<<B_, 256, 0, stream>>>(x, xw, zh, b_y, lna_g, lna_b, log_damp, k, acond_bf);
    // y = relu(acond @ D_y) * x  -> bf16
    gemm_mfma<1><<<dim3(32, 8, 1), 256, 0, stream>>>(acond_bf, DyT, nullptr, x,
                                                     nullptr, nullptr, y_bf, 256, 2048, 256);
    // z_pre = y @ E (split-K 8)
    gemm_mfma<2><<<dim3(4, 8, 8), 256, 0, stream>>>(y_bf, ET, nullptr, nullptr,
                                                    nullptr, zparts, nullptr, 2048, 256, 256);
    // z = LN(sum parts); zbx = bf16(z + b_x)
    k_ln_reduce<<<B_, 256, 0, stream>>>(zparts, 8, B_ * D_, nullptr, 0, lnz_g, lnz_b,
                                        b_x, zh + (size_t)k * B_ * D_, zbx_bf);
    // x += relu(zbx @ D_x)
    gemm_mfma<3><<<dim3(32, 8, 1), 256, 0, stream>>>(zbx_bf, DxT, nullptr, nullptr,
                                                     x, x, nullptr, 256, 2048, 256);
  }

  // ---- value head (f32) ----
  gemm_tile<2><<<dim3(2, 8, 1), 256, 0, stream>>>(zh + (size_t)(KSTEPS - 1) * B_ * D_,
                                                  vh_w1, vh_b1, gbuf, B_, 128, D_, D_);
  k_value2<<<4, 128, 0, stream>>>(gbuf, vh_w2, vh_b2, outp);
}

// Round 3
// 413.671 us; speedup vs baseline: 2.0382x; 1.0879x over previous
//
#include <hip/hip_runtime.h>
#include <hip/hip_bf16.h>
#include <math.h>

#define B_ 512
#define D_ 256
#define NH_ 4
#define NN_ 512
#define NTOT_ 2048
#define DH_ 64
#define KSTEPS 8

typedef __attribute__((ext_vector_type(8))) short bf16x8;
typedef __attribute__((ext_vector_type(4))) float f32x4;

#if __has_builtin(__builtin_amdgcn_global_load_lds)
#define HAVE_GLL 1
#else
#define HAVE_GLL 0
#endif

__device__ __forceinline__ float gelu_exact(float x) {
  return 0.5f * x * (1.0f + erff(x * 0.70710678118654752f));
}

__device__ __forceinline__ unsigned short f2b(float f) {
  union { float f; unsigned int u; } x; x.f = f;
  unsigned int u = x.u;
  unsigned int r = (u + 0x7FFFu + ((u >> 16) & 1u)) >> 16;
  return (unsigned short)r;
}

__device__ __forceinline__ float blockReduceSum256(float v, float* red) {
  int t = threadIdx.x;
  red[t] = v; __syncthreads();
  #pragma unroll
  for (int st = 128; st > 0; st >>= 1) {
    if (t < st) red[t] += red[t + st];
    __syncthreads();
  }
  float r = red[0];
  __syncthreads();
  return r;
}

#if HAVE_GLL
__device__ __forceinline__ void load16_lds(const unsigned short* g, unsigned short* l) {
  __builtin_amdgcn_global_load_lds(
      (const __attribute__((address_space(1))) unsigned int*)g,
      (__attribute__((address_space(3))) unsigned int*)l, 16, 0, 0);
}
#endif

// ---------------- bf16 MFMA GEMM v2 ----------------
// A [M][K] bf16 row-major (row stride K), W [N][K] bf16 row-major.
// Tile 64 rows x 32 cols, BK=64, 256 threads (4 waves, each 16 rows x 32 cols).
// EPI: 0 = bias + relu -> f32
//      1 = relu * mul  -> bf16
//      2 = raw partial (split-K part blockIdx.z) -> f32 (+z*512*N)
//      3 = relu + addto -> f32
template<int EPI>
__global__ __launch_bounds__(256) void gemm_mfma(
    const unsigned short* __restrict__ A, const unsigned short* __restrict__ W,
    const float* __restrict__ bias, const float* __restrict__ mul,
    const float* __restrict__ addto, float* __restrict__ outf,
    unsigned short* __restrict__ outb, int K, int N, int kchunk)
{
  __shared__ __align__(16) unsigned short As[2][64 * 64];
  __shared__ __align__(16) unsigned short Ws[2][32 * 64];
  const int t = threadIdx.x;
  const int lane = t & 63;
  const int w = t >> 6;
  const int row0 = blockIdx.y * 64, col0 = blockIdx.x * 32;
  const int k0 = blockIdx.z * kchunk;
  const int nt = kchunk >> 6;
  const int lr = lane & 15, lk = lane >> 4;
  const int l3 = lane >> 3, cch = lane & 7;

  f32x4 acc[2];
  acc[0] = (f32x4){0.f, 0.f, 0.f, 0.f};
  acc[1] = (f32x4){0.f, 0.f, 0.f, 0.f};

#if HAVE_GLL
  // ---- async staging: LDS dest linear, global source pre-swizzled ----
  #define STAGE(tt)                                                              \
    {                                                                            \
      int buf_ = (tt) & 1;                                                       \
      int kk_ = k0 + (tt) * 64;                                                  \
      _Pragma("unroll")                                                          \
      for (int p = 0; p < 2; p++) {                                              \
        int r_ = (w * 2 + p) * 8 + l3;                                           \
        load16_lds(&A[(size_t)(row0 + r_) * K + kk_ + ((cch ^ (r_ & 7)) << 3)],  \
                   &As[buf_][(w * 2 + p) * 512]);                                \
      }                                                                          \
      int rw_ = w * 8 + l3;                                                      \
      load16_lds(&W[(size_t)(col0 + rw_) * K + kk_ + ((cch ^ (rw_ & 7)) << 3)],  \
                 &Ws[buf_][w * 512]);                                            \
    }

  STAGE(0);
  for (int tt = 0; tt < nt; tt++) {
    asm volatile("s_waitcnt vmcnt(0)" ::: "memory");
    __builtin_amdgcn_s_barrier();
    asm volatile("" ::: "memory");
    if (tt + 1 < nt) STAGE(tt + 1);
    const unsigned short* Ab = As[tt & 1];
    const unsigned short* Wb = Ws[tt & 1];
    #pragma unroll
    for (int ks = 0; ks < 2; ks++) {
      int q = ks * 4 + lk;
      int r = w * 16 + lr;
      bf16x8 af = *(const bf16x8*)&Ab[r * 64 + ((q ^ (r & 7)) << 3)];
      #pragma unroll
      for (int j = 0; j < 2; j++) {
        int c = j * 16 + lr;
        bf16x8 bf = *(const bf16x8*)&Wb[c * 64 + ((q ^ (c & 7)) << 3)];
        acc[j] = __builtin_amdgcn_mfma_f32_16x16x32_bf16(af, bf, acc[j], 0, 0, 0);
      }
    }
  }
  #undef STAGE
#else
  // ---- sync fallback: reg staging, full barriers ----
  for (int tt = 0; tt < nt; tt++) {
    int buf_ = tt & 1;
    int kk_ = k0 + tt * 64;
    #pragma unroll
    for (int p = 0; p < 2; p++) {
      int r_ = (w * 2 + p) * 8 + l3;
      bf16x8 v = *(const bf16x8*)&A[(size_t)(row0 + r_) * K + kk_ + ((cch ^ (r_ & 7)) << 3)];
      *(bf16x8*)&As[buf_][r_ * 64 + (cch << 3)] = v;
    }
    int rw_ = w * 8 + l3;
    bf16x8 vw = *(const bf16x8*)&W[(size_t)(col0 + rw_) * K + kk_ + ((cch ^ (rw_ & 7)) << 3)];
    *(bf16x8*)&Ws[buf_][rw_ * 64 + (cch << 3)] = vw;
    __syncthreads();
    const unsigned short* Ab = As[buf_];
    const unsigned short* Wb = Ws[buf_];
    #pragma unroll
    for (int ks = 0; ks < 2; ks++) {
      int q = ks * 4 + lk;
      int r = w * 16 + lr;
      bf16x8 af = *(const bf16x8*)&Ab[r * 64 + ((q ^ (r & 7)) << 3)];
      #pragma unroll
      for (int j = 0; j < 2; j++) {
        int c = j * 16 + lr;
        bf16x8 bf = *(const bf16x8*)&Wb[c * 64 + ((q ^ (c & 7)) << 3)];
        acc[j] = __builtin_amdgcn_mfma_f32_16x16x32_bf16(af, bf, acc[j], 0, 0, 0);
      }
    }
    __syncthreads();
  }
#endif

  const int cr = lk * 4;
  #pragma unroll
  for (int j = 0; j < 2; j++) {
    #pragma unroll
    for (int q = 0; q < 4; q++) {
      int r = row0 + w * 16 + cr + q;
      int c = col0 + j * 16 + lr;
      float v = acc[j][q];
      if (EPI == 0) {
        v += bias[c]; v = fmaxf(v, 0.f);
        outf[(size_t)r * N + c] = v;
      } else if (EPI == 1) {
        v = fmaxf(v, 0.f) * mul[(size_t)r * N + c];
        outb[(size_t)r * N + c] = f2b(v);
      } else if (EPI == 2) {
        outf[(size_t)blockIdx.z * ((size_t)512 * N) + (size_t)r * N + c] = v;
      } else {
        v = fmaxf(v, 0.f) + addto[(size_t)r * N + c];
        outf[(size_t)r * N + c] = v;
      }
    }
  }
}

// ---------------- f32 tiled GEMM (encoder / misc) ----------------
// ACT: 0 none, 2 gelu. Split-K when gridDim.z > 1 (raw partials, no epilogue).
// outb (optional): also write bf16 copy.
template<int ACT>
__global__ __launch_bounds__(256) void gemm_tile(
    const float* __restrict__ A, const float* __restrict__ W,
    const float* __restrict__ bias, float* __restrict__ out,
    unsigned short* __restrict__ outb, int M, int N, int K, int kchunk)
{
  __shared__ float As[16][68];
  __shared__ float Bs[16][68];
  const int tid = threadIdx.x;
  const int row0 = blockIdx.y * 64;
  const int col0 = blockIdx.x * 64;
  const int k0 = blockIdx.z * kchunk;
  const int ty = tid >> 4, tx = tid & 15;
  const int ar = tid >> 4, ak = tid & 15;
  const int br = tid >> 6, bc = tid & 63;
  float acc[4][4] = {};
  for (int kk = k0; kk < k0 + kchunk; kk += 16) {
    #pragma unroll
    for (int i = 0; i < 4; i++) {
      int r = ar + i * 16;
      As[ak][r] = A[(size_t)(row0 + r) * K + kk + ak];
    }
    #pragma unroll
    for (int i = 0; i < 4; i++) {
      int kr = br + i * 4;
      Bs[kr][bc] = W[(size_t)(kk + kr) * N + col0 + bc];
    }
    __syncthreads();
    #pragma unroll
    for (int q = 0; q < 16; q++) {
      float4 av = *(const float4*)&As[q][ty * 4];
      float4 bv = *(const float4*)&Bs[q][tx * 4];
      float aa[4] = {av.x, av.y, av.z, av.w};
      float bb[4] = {bv.x, bv.y, bv.z, bv.w};
      #pragma unroll
      for (int i = 0; i < 4; i++)
        #pragma unroll
        for (int j = 0; j < 4; j++)
          acc[i][j] = fmaf(aa[i], bb[j], acc[i][j]);
    }
    __syncthreads();
  }
  const bool parts = (gridDim.z > 1);
  float* o = out + (parts ? (size_t)blockIdx.z * (size_t)M * N : (size_t)0);
  #pragma unroll
  for (int i = 0; i < 4; i++) {
    int r = row0 + ty * 4 + i;
    #pragma unroll
    for (int j = 0; j < 4; j++) {
      int c = col0 + tx * 4 + j;
      float v = acc[i][j];
      if (!parts) {
        if (bias) v += bias[c];
        if (ACT == 2) v = gelu_exact(v);
      }
      o[(size_t)r * N + c] = v;
      if (!parts && outb) outb[(size_t)r * N + c] = f2b(v);
    }
  }
}

// ---------------- unified weight prep: transpose + f32->bf16 ----------------
// blockIdx.y selects weight; out[n][k] bf16 (row stride Kd).
__global__ __launch_bounds__(256) void k_prep(
    const float* __restrict__ D_y, const float* __restrict__ D_x,
    const float* __restrict__ xinit_w, const float* __restrict__ E,
    unsigned short* __restrict__ DyT, unsigned short* __restrict__ DxT,
    unsigned short* __restrict__ xinitT, unsigned short* __restrict__ ET)
{
  __shared__ float T[64][65];
  const float* in; unsigned short* out; int Kd, Nd, head, nx;
  switch (blockIdx.y) {
    case 0:  in = D_y;     out = DyT;    Kd = 256;  Nd = 2048; head = 1; nx = 32; break;
    case 1:  in = D_x;     out = DxT;    Kd = 256;  Nd = 2048; head = 1; nx = 32; break;
    case 2:  in = xinit_w; out = xinitT; Kd = 256;  Nd = 2048; head = 0; nx = 32; break;
    default: in = E;       out = ET;     Kd = 2048; Nd = 256;  head = 0; nx = 4;  break;
  }
  const int n0 = (blockIdx.x % nx) * 64, k0 = (blockIdx.x / nx) * 64;
  const int tx = threadIdx.x & 63, ty = threadIdx.x >> 6;
  #pragma unroll
  for (int i = 0; i < 16; i++) {
    int k = k0 + ty + i * 4;
    int n = n0 + tx;
    float v;
    if (head) v = in[((size_t)(n >> 9) * 256 + k) * 512 + (n & 511)];
    else      v = in[(size_t)k * Nd + n];
    T[ty + i * 4][tx] = v;
  }
  __syncthreads();
  #pragma unroll
  for (int i = 0; i < 16; i++) {
    int n = n0 + ty + i * 4;
    out[(size_t)n * Kd + k0 + tx] = f2b(T[tx][ty + i * 4]);
  }
}

// ---------------- LN with partial-sum reduce ----------------
__global__ __launch_bounds__(256) void k_ln_reduce(
    const float* __restrict__ in, int nparts, int stride,
    const float* __restrict__ pre_bias, int do_gelu,
    const float* __restrict__ g, const float* __restrict__ bta,
    const float* __restrict__ addvec, float* __restrict__ out,
    unsigned short* __restrict__ out2_bf)
{
  __shared__ float red[256];
  int b = blockIdx.x, d = threadIdx.x;
  float v = 0.f;
  for (int p = 0; p < nparts; p++) v += in[(size_t)p * stride + (size_t)b * 256 + d];
  if (pre_bias) v += pre_bias[d];
  if (do_gelu) v = gelu_exact(v);
  float mu = blockReduceSum256(v, red) * (1.f / 256.f);
  float c = v - mu;
  float var = blockReduceSum256(c * c, red) * (1.f / 256.f);
  float vn = c * rsqrtf(var + 1e-5f) * g[d] + bta[d];
  out[(size_t)b * 256 + d] = vn;
  if (out2_bf) out2_bf[(size_t)b * 256 + d] = f2b(vn + addvec[(size_t)b * 256 + d]);
}

// ---------------- step_a: xw(k-1) + low-rank rho dots + LN -> acond (bf16) ----------------
__global__ __launch_bounds__(256) void step_a(
    const float* __restrict__ x, float* __restrict__ xw_hist,
    const float* __restrict__ z_hist, const float* __restrict__ b_y,
    const float* __restrict__ lna_g, const float* __restrict__ lna_b,
    const float* __restrict__ log_damp, int k, unsigned short* __restrict__ out)
{
  __shared__ float dots[KSTEPS][NH_];
  __shared__ float red[256];
  int b = blockIdx.x, t = threadIdx.x;
  int lane = t & 63, wv = t >> 6;  // wv == head
  float lam = 1.f / (1.f + expf(-log_damp[0]));
  const float* xb = x + (size_t)b * NTOT_;
  float xv[8];
  #pragma unroll
  for (int i = 0; i < 8; i++) xv[i] = xb[t * 8 + i];

  if (k >= 1) {
    float s = 0.f;
    #pragma unroll
    for (int i = 0; i < 8; i++) s += xv[i] * xv[i];
    #pragma unroll
    for (int m = 1; m < 64; m <<= 1) s += __shfl_xor(s, m, 64);
    float inv = 1.f / (sqrtf(s) + 1e-8f);
    float* xwout = xw_hist + ((size_t)(k - 1) * B_ + b) * NTOT_;
    #pragma unroll
    for (int i = 0; i < 8; i++) xwout[t * 8 + i] = xv[i] * inv;
    if (lane == 0) dots[k - 1][wv] = s * inv;
  }
  for (int j = 0; j < k - 1; j++) {
    const float* xwb = xw_hist + ((size_t)j * B_ + b) * NTOT_;
    float s = 0.f;
    #pragma unroll
    for (int i = 0; i < 8; i++) s += xv[i] * xwb[t * 8 + i];
    #pragma unroll
    for (int off = 32; off > 0; off >>= 1) s += __shfl_down(s, off, 64);
    if (lane == 0) dots[j][wv] = s;
  }
  __syncthreads();

  int d = t;
  float av = 0.f, lp = 1.f;
  for (int j = k - 1; j >= 0; j--) {
    av += (1.f - lam) * lp * dots[j][d >> 6] * z_hist[((size_t)j * B_ + b) * D_ + d];
    lp *= lam;
  }
  av += b_y[(size_t)b * D_ + d];
  float mu = blockReduceSum256(av, red) * (1.f / 256.f);
  float c = av - mu;
  float var = blockReduceSum256(c * c, red) * (1.f / 256.f);
  out[(size_t)b * D_ + d] = f2b(c * rsqrtf(var + 1e-5f) * lna_g[d] + lna_b[d]);
}

// ---------------- fused value head: v = tanh(gelu(z@W1+b1)@w2 + b2) ----------------
__global__ __launch_bounds__(128) void k_value(
    const float* __restrict__ z, const float* __restrict__ w1,
    const float* __restrict__ b1, const float* __restrict__ w2,
    const float* __restrict__ b2, float* __restrict__ out)
{
  __shared__ float red[128];
  int b = blockIdx.x, j = threadIdx.x;
  const float* zr = z + (size_t)b * 256;
  float s = 0.f;
  #pragma unroll 8
  for (int i = 0; i < 256; i++) s += zr[i] * w1[(size_t)i * 128 + j];
  float g = gelu_exact(s + b1[j]) * w2[j];
  red[j] = g; __syncthreads();
  #pragma unroll
  for (int st = 64; st > 0; st >>= 1) {
    if (j < st) red[j] += red[j + st];
    __syncthreads();
  }
  if (j == 0) out[b] = tanhf(red[0] + b2[0]);
}

extern "C" void kernel_launch(void* const* d_in, const int* in_sizes, int n_in,
                              void* d_out, int out_size, void* d_ws, size_t ws_size,
                              hipStream_t stream) {
  const float* boards   = (const float*)d_in[0];
  const float* enc_w1   = (const float*)d_in[1];
  const float* enc_b1   = (const float*)d_in[2];
  const float* enc_ln_g = (const float*)d_in[3];
  const float* enc_ln_b = (const float*)d_in[4];
  const float* enc_w2   = (const float*)d_in[5];
  const float* enc_b2   = (const float*)d_in[6];
  const float* xinit_w  = (const float*)d_in[7];
  const float* xinit_b  = (const float*)d_in[8];
  const float* D_y      = (const float*)d_in[9];
  const float* E        = (const float*)d_in[10];
  const float* D_x      = (const float*)d_in[11];
  const float* By_w     = (const float*)d_in[12];
  const float* Bx_w     = (const float*)d_in[13];
  const float* lna_g    = (const float*)d_in[14];
  const float* lna_b    = (const float*)d_in[15];
  const float* lnz_g    = (const float*)d_in[16];
  const float* lnz_b    = (const float*)d_in[17];
  const float* log_damp = (const float*)d_in[18];
  const float* vh_w1    = (const float*)d_in[19];
  const float* vh_b1    = (const float*)d_in[20];
  const float* vh_w2    = (const float*)d_in[21];
  const float* vh_b2    = (const float*)d_in[22];
  float* outp = (float*)d_out;

  float* ws = (float*)d_ws;
  size_t o = 0;
  float* x      = ws + o; o += (size_t)B_ * NTOT_;
  float* xw     = ws + o; o += (size_t)KSTEPS * B_ * NTOT_;
  float* zh     = ws + o; o += (size_t)KSTEPS * B_ * D_;
  float* hparts = ws + o; o += (size_t)8 * B_ * D_;
  float* h      = ws + o; o += (size_t)B_ * D_;
  float* bvec   = ws + o; o += (size_t)B_ * D_;
  float* b_y    = ws + o; o += (size_t)B_ * D_;
  float* b_x    = ws + o; o += (size_t)B_ * D_;
  float* zparts = ws + o; o += (size_t)8 * B_ * D_;
  unsigned short* DyT     = (unsigned short*)(ws + o); o += (size_t)NTOT_ * D_ / 2;
  unsigned short* DxT     = (unsigned short*)(ws + o); o += (size_t)NTOT_ * D_ / 2;
  unsigned short* ET      = (unsigned short*)(ws + o); o += (size_t)D_ * NTOT_ / 2;
  unsigned short* xinitT  = (unsigned short*)(ws + o); o += (size_t)NTOT_ * D_ / 2;
  unsigned short* bvec_bf = (unsigned short*)(ws + o); o += (size_t)B_ * D_ / 2;
  unsigned short* acond_bf= (unsigned short*)(ws + o); o += (size_t)B_ * D_ / 2;
  unsigned short* zbx_bf  = (unsigned short*)(ws + o); o += (size_t)B_ * D_ / 2;
  unsigned short* y_bf    = (unsigned short*)(ws + o); o += (size_t)B_ * NTOT_ / 2;

  // ---- one-time weight prep (bf16, transposed to [N][K]) ----
  k_prep<<<dim3(128, 4), 256, 0, stream>>>(D_y, D_x, xinit_w, E, DyT, DxT, xinitT, ET);

  // ---- encoder (f32) ----
  gemm_tile<0><<<dim3(4, 8, 8), 256, 0, stream>>>(boards, enc_w1, nullptr, hparts,
                                                  nullptr, B_, D_, 768, 96);
  k_ln_reduce<<<B_, 256, 0, stream>>>(hparts, 8, B_ * D_, enc_b1, 1,
                                      enc_ln_g, enc_ln_b, nullptr, h, nullptr);
  gemm_tile<0><<<dim3(4, 8, 1), 256, 0, stream>>>(h, enc_w2, enc_b2, bvec, bvec_bf,
                                                  B_, D_, D_, D_);
  gemm_tile<0><<<dim3(4, 8, 1), 256, 0, stream>>>(bvec, By_w, nullptr, b_y, nullptr,
                                                  B_, D_, D_, D_);
  gemm_tile<0><<<dim3(4, 8, 1), 256, 0, stream>>>(bvec, Bx_w, nullptr, b_x, nullptr,
                                                  B_, D_, D_, D_);
  // x0 = relu(b @ xinit_w + bias)
  gemm_mfma<0><<<dim3(64, 8, 1), 256, 0, stream>>>(bvec_bf, xinitT, xinit_b, nullptr,
                                                   nullptr, x, nullptr, 256, 2048, 256);

  // ---- K thinking steps ----
  for (int k = 0; k < KSTEPS; k++) {
    step_a<<<B_, 256, 0, stream>>>(x, xw, zh, b_y, lna_g, lna_b, log_damp, k, acond_bf);
    // y = relu(acond @ D_y) * x  -> bf16
    gemm_mfma<1><<<dim3(64, 8, 1), 256, 0, stream>>>(acond_bf, DyT, nullptr, x,
                                                     nullptr, nullptr, y_bf, 256, 2048, 256);
    // z_pre = y @ E (split-K 8)
    gemm_mfma<2><<<dim3(8, 8, 8), 256, 0, stream>>>(y_bf, ET, nullptr, nullptr,
                                                    nullptr, zparts, nullptr, 2048, 256, 256);
    // z = LN(sum parts); zbx = bf16(z + b_x)
    k_ln_reduce<<<B_, 256, 0, stream>>>(zparts, 8, B_ * D_, nullptr, 0, lnz_g, lnz_b,
                                        b_x, zh + (size_t)k * B_ * D_, zbx_bf);
    // x += relu(zbx @ D_x)
    gemm_mfma<3><<<dim3(64, 8, 1), 256, 0, stream>>>(zbx_bf, DxT, nullptr, nullptr,
                                                     x, x, nullptr, 256, 2048, 256);
  }

  // ---- value head ----
  k_value<<<B_, 128, 0, stream>>>(zh + (size_t)(KSTEPS - 1) * B_ * D_,
                                  vh_w1, vh_b1, vh_w2, vh_b2, outp);
}